// Round 1
// baseline (270.417 us; speedup 1.0000x reference)
//
#include <hip/hip_runtime.h>
#include <hip/hip_bf16.h>

// GraphSAGE: out = normalize( [x, segsum(vals*x[cols], rows)] @ W^T + b )
// N=100000, E=1600000, IN_F=128, OUT_F=128.
//
// ws layout:
//   [0          , 400004)    row_ptr  (int[N+1])
//   [448K       , 512K)      W_bf16   (128x256 bf16 = 64KB)
//   [640K       , 640K+51.2M) comb_bf16 (N x 256 bf16): [:,0:128]=bf16(x), [:,128:256]=neighbor

typedef __bf16 bf16x8_t __attribute__((ext_vector_type(8)));
typedef float f32x4_t __attribute__((ext_vector_type(4)));

__device__ __forceinline__ unsigned int f32_to_bf16(float f) {
    unsigned int u = __float_as_uint(f);
    unsigned int r = u + 0x7fffu + ((u >> 16) & 1u);   // RNE (no NaN inputs)
    return r >> 16;
}
__device__ __forceinline__ float bf16lo_to_f32(unsigned int p) {
    return __uint_as_float(p << 16);
}
__device__ __forceinline__ float bf16hi_to_f32(unsigned int p) {
    return __uint_as_float(p & 0xffff0000u);
}

// --- K0: row_ptr[n] = lower_bound(rows, n), n in [0, N] -------------------
__global__ void rowptr_kernel(const int* __restrict__ rows, int* __restrict__ row_ptr,
                              int Nn, int Ee) {
    int n = blockIdx.x * blockDim.x + threadIdx.x;
    if (n > Nn) return;
    int lo = 0, hi = Ee;
    while (lo < hi) {
        int mid = (lo + hi) >> 1;
        if (rows[mid] < n) lo = mid + 1; else hi = mid;
    }
    row_ptr[n] = lo;
}

// --- K1: W (fp32 [128,256]) -> bf16 packed ---------------------------------
__global__ void wcast_kernel(const float* __restrict__ W, unsigned int* __restrict__ Wb_u) {
    int i = blockIdx.x * blockDim.x + threadIdx.x;   // 16384 threads, 2 floats each
    float2 f2 = ((const float2*)W)[i];
    Wb_u[i] = f32_to_bf16(f2.x) | (f32_to_bf16(f2.y) << 16);
}

// --- K2: x -> bf16 into comb[:,0:128] --------------------------------------
__global__ void xcast_kernel(const float* __restrict__ x, unsigned int* __restrict__ comb_u,
                             int total /* N*64 */) {
    int i = blockIdx.x * blockDim.x + threadIdx.x;
    if (i >= total) return;
    int n = i >> 6, t = i & 63;
    float2 f2 = ((const float2*)x)[(size_t)n * 64 + t];
    comb_u[(size_t)n * 128 + t] = f32_to_bf16(f2.x) | (f32_to_bf16(f2.y) << 16);
}

// --- K3: neighbor[n,:] = sum_{e in row n} vals[e] * xbf16[cols[e],:] -------
// one wave (64 threads) per node; each lane owns 2 features (one packed uint)
__global__ __launch_bounds__(64) void agg_kernel(const int* __restrict__ row_ptr,
                                                 const int* __restrict__ cols,
                                                 const float* __restrict__ vals,
                                                 unsigned int* __restrict__ comb_u) {
    int n = blockIdx.x;
    int t = threadIdx.x;                 // 0..63
    int start = row_ptr[n], end = row_ptr[n + 1];
    float a0 = 0.f, a1 = 0.f;
    int e = start;
    for (; e + 1 < end; e += 2) {        // 2 gathers in flight
        int   c0 = cols[e],     c1 = cols[e + 1];
        float v0 = vals[e],     v1 = vals[e + 1];
        unsigned int p0 = comb_u[(size_t)c0 * 128 + t];
        unsigned int p1 = comb_u[(size_t)c1 * 128 + t];
        a0 += v0 * bf16lo_to_f32(p0);  a1 += v0 * bf16hi_to_f32(p0);
        a0 += v1 * bf16lo_to_f32(p1);  a1 += v1 * bf16hi_to_f32(p1);
    }
    if (e < end) {
        int c = cols[e]; float v = vals[e];
        unsigned int p = comb_u[(size_t)c * 128 + t];
        a0 += v * bf16lo_to_f32(p);  a1 += v * bf16hi_to_f32(p);
    }
    comb_u[(size_t)n * 128 + 64 + t] = f32_to_bf16(a0) | (f32_to_bf16(a1) << 16);
}

// --- K4: out = normalize(comb @ W^T + b); MFMA bf16, fused epilogue --------
// block = 256 thr = 4 waves; each wave: 16 rows x 128 cols, K=256.
// A frag: lane holds comb[r0 + (lane&15)][ks*32 + (lane>>4)*8 ..+8]   (16B contiguous)
// B frag: lane holds W  [t*16 + (lane&15)][ks*32 + (lane>>4)*8 ..+8]  (16B contiguous)
// C/D:    col = lane&15 (+16*t), row = (lane>>4)*4 + reg              [m89 layout]
__global__ __launch_bounds__(256) void gemm_norm_kernel(
        const unsigned short* __restrict__ comb, const unsigned short* __restrict__ Wb,
        const float* __restrict__ b, float* __restrict__ out, int Nn) {
    int lane = threadIdx.x & 63;
    int wave = threadIdx.x >> 6;
    int m    = lane & 15;
    int quad = lane >> 4;
    int r0   = (blockIdx.x * 4 + wave) * 16;

    int arow = r0 + m;
    if (arow >= Nn) arow = Nn - 1;       // clamp; stores are guarded below
    const bf16x8_t* A = (const bf16x8_t*)(comb + (size_t)arow * 256);

    bf16x8_t a[8];
#pragma unroll
    for (int ks = 0; ks < 8; ++ks) a[ks] = A[ks * 4 + quad];

    f32x4_t acc[8];
#pragma unroll
    for (int t = 0; t < 8; ++t) acc[t] = (f32x4_t){0.f, 0.f, 0.f, 0.f};

#pragma unroll
    for (int t = 0; t < 8; ++t) {
        const bf16x8_t* B = (const bf16x8_t*)(Wb + (size_t)(t * 16 + m) * 256);
#pragma unroll
        for (int ks = 0; ks < 8; ++ks) {
            acc[t] = __builtin_amdgcn_mfma_f32_16x16x32_bf16(a[ks], B[ks * 4 + quad], acc[t], 0, 0, 0);
        }
    }

    float bc[8];
#pragma unroll
    for (int t = 0; t < 8; ++t) bc[t] = b[t * 16 + m];

    // per-row sum of squares: lane holds rows quad*4+r, cols t*16+m
    float sq[4] = {0.f, 0.f, 0.f, 0.f};
#pragma unroll
    for (int t = 0; t < 8; ++t)
#pragma unroll
        for (int r = 0; r < 4; ++r) {
            float v = acc[t][r] + bc[t];
            sq[r] += v * v;
        }
    // reduce across the 16 lanes sharing a quad (xor bits 0..3)
#pragma unroll
    for (int off = 1; off <= 8; off <<= 1) {
#pragma unroll
        for (int r = 0; r < 4; ++r) sq[r] += __shfl_xor(sq[r], off, 64);
    }
    float scale[4];
#pragma unroll
    for (int r = 0; r < 4; ++r) {
        float nrm = sqrtf(sq[r]);
        scale[r] = 1.f / fmaxf(nrm, 1e-12f);
    }

#pragma unroll
    for (int r = 0; r < 4; ++r) {
        int row = r0 + quad * 4 + r;
        if (row < Nn) {
            float* orow = out + (size_t)row * 128;
#pragma unroll
            for (int t = 0; t < 8; ++t) {
                float v = acc[t][r] + bc[t];
                orow[t * 16 + m] = v * scale[r];
            }
        }
    }
}

extern "C" void kernel_launch(void* const* d_in, const int* in_sizes, int n_in,
                              void* d_out, int out_size, void* d_ws, size_t ws_size,
                              hipStream_t stream) {
    const float* x    = (const float*)d_in[0];
    const int*   rows = (const int*)  d_in[1];
    const int*   cols = (const int*)  d_in[2];
    const float* vals = (const float*)d_in[3];
    const float* W    = (const float*)d_in[4];
    const float* b    = (const float*)d_in[5];
    float*       out  = (float*)d_out;

    const int Nn = in_sizes[0] / 128;    // 100000
    const int Ee = in_sizes[1];          // 1600000

    char* ws = (char*)d_ws;
    int*          row_ptr = (int*)ws;
    unsigned int* Wb_u    = (unsigned int*)(ws + 448 * 1024);
    unsigned int* comb_u  = (unsigned int*)(ws + 640 * 1024);
    const unsigned short* Wb   = (const unsigned short*)Wb_u;
    const unsigned short* comb = (const unsigned short*)comb_u;

    rowptr_kernel<<<(Nn + 256) / 256, 256, 0, stream>>>(rows, row_ptr, Nn, Ee);
    wcast_kernel<<<64, 256, 0, stream>>>(W, Wb_u);
    xcast_kernel<<<(Nn * 64 + 255) / 256, 256, 0, stream>>>(x, comb_u, Nn * 64);
    agg_kernel<<<Nn, 64, 0, stream>>>(row_ptr, cols, vals, comb_u);
    gemm_norm_kernel<<<(Nn + 63) / 64, 256, 0, stream>>>(comb, Wb, b, out, Nn);
}

// Round 2
// 209.987 us; speedup vs baseline: 1.2878x; 1.2878x over previous
//
#include <hip/hip_runtime.h>
#include <hip/hip_bf16.h>

// GraphSAGE: out = normalize( [x, segsum(vals*x[cols], rows)] @ W^T + b )
// N=100000, E=1600000, IN_F=128, OUT_F=128.
//
// ws layout:
//   [0    , ~400K)  row_ptr (int[N+1])
//   [448K , 512K)   Wf: fragment-major bf16 W, 4096 x 16B
//   [640K , +25.6M) xb: bf16(x), N x 128 (packed uint2 rows of 32)
//   [next , +25.6M) nb: neighbor bf16, N x 128

typedef __bf16 bf16x8_t __attribute__((ext_vector_type(8)));
typedef float f32x4_t __attribute__((ext_vector_type(4)));

__device__ __forceinline__ unsigned int f32_to_bf16(float f) {
    unsigned int u = __float_as_uint(f);
    unsigned int r = u + 0x7fffu + ((u >> 16) & 1u);   // RNE (no NaN inputs)
    return r >> 16;
}
__device__ __forceinline__ unsigned int pack2(float a, float b) {
    return f32_to_bf16(a) | (f32_to_bf16(b) << 16);
}
__device__ __forceinline__ float bflo(unsigned int p) { return __uint_as_float(p << 16); }
__device__ __forceinline__ float bfhi(unsigned int p) { return __uint_as_float(p & 0xffff0000u); }

// --- K0: row_ptr[n] = lower_bound(rows, n) ---------------------------------
__global__ void rowptr_kernel(const int* __restrict__ rows, int* __restrict__ row_ptr,
                              int Nn, int Ee) {
    int n = blockIdx.x * blockDim.x + threadIdx.x;
    if (n > Nn) return;
    int lo = 0, hi = Ee;
    while (lo < hi) {
        int mid = (lo + hi) >> 1;
        if (rows[mid] < n) lo = mid + 1; else hi = mid;
    }
    row_ptr[n] = lo;
}

// --- K1: W fp32 [128,256] -> fragment-major bf16 ---------------------------
// Wf[(t*8+ks)*64 + lane] = bf16x8 of W[t*16+(lane&15)][ks*32+(lane>>4)*8 ..+8]
__global__ void wcast_kernel(const float* __restrict__ W, uint4* __restrict__ Wf) {
    int i = blockIdx.x * blockDim.x + threadIdx.x;   // 0..4095
    int lane = i & 63, ks = (i >> 6) & 7, t = i >> 9;
    int row = t * 16 + (lane & 15);
    int col = ks * 32 + (lane >> 4) * 8;
    const float* p = W + (size_t)row * 256 + col;
    uint4 o;
    o.x = pack2(p[0], p[1]); o.y = pack2(p[2], p[3]);
    o.z = pack2(p[4], p[5]); o.w = pack2(p[6], p[7]);
    Wf[i] = o;
}

// --- K2: x -> bf16 xb ------------------------------------------------------
__global__ void xcast_kernel(const float* __restrict__ x, uint2* __restrict__ xb,
                             int total /* N*32 */) {
    int i = blockIdx.x * blockDim.x + threadIdx.x;
    if (i >= total) return;
    float4 f = ((const float4*)x)[i];
    uint2 o; o.x = pack2(f.x, f.y); o.y = pack2(f.z, f.w);
    xb[i] = o;
}

// --- K3: nb[n,:] = sum_{e in row n} vals[e] * xb[cols[e],:] ----------------
// one wave per node; half-wave per edge (8B/lane gathers), 8 edges/group,
// 2-stage pipeline prefetching next group's cols/vals.
__global__ __launch_bounds__(64) void agg_kernel(const int* __restrict__ row_ptr,
                                                 const int* __restrict__ cols,
                                                 const float* __restrict__ vals,
                                                 const uint2* __restrict__ xb,
                                                 uint2* __restrict__ nb) {
    int n = blockIdx.x;
    int lane = threadIdx.x;
    int h = lane >> 5;          // which edge of the pair this half-wave handles
    int l = lane & 31;          // covers features [4l, 4l+4)
    int start = row_ptr[n], end = row_ptr[n + 1];
    float a0 = 0.f, a1 = 0.f, a2 = 0.f, a3 = 0.f;

    int c0 = 0, c1 = 0, c2 = 0, c3 = 0;
    float v0 = 0.f, v1 = 0.f, v2 = 0.f, v3 = 0.f;

#define LOADG(E, C0, C1, C2, C3, V0, V1, V2, V3)                                   \
    {                                                                              \
        int m0 = (E) + h, m1 = (E) + 2 + h, m2 = (E) + 4 + h, m3 = (E) + 6 + h;    \
        int q0 = min(m0, end - 1), q1 = min(m1, end - 1);                          \
        int q2 = min(m2, end - 1), q3 = min(m3, end - 1);                          \
        C0 = cols[q0]; C1 = cols[q1]; C2 = cols[q2]; C3 = cols[q3];                \
        V0 = (m0 < end) ? vals[q0] : 0.f; V1 = (m1 < end) ? vals[q1] : 0.f;        \
        V2 = (m2 < end) ? vals[q2] : 0.f; V3 = (m3 < end) ? vals[q3] : 0.f;        \
    }

    int e = start;
    if (e < end) LOADG(e, c0, c1, c2, c3, v0, v1, v2, v3);
    while (e < end) {
        int en = e + 8;
        int d0 = 0, d1 = 0, d2 = 0, d3 = 0;
        float w0 = 0.f, w1 = 0.f, w2 = 0.f, w3 = 0.f;
        if (en < end) LOADG(en, d0, d1, d2, d3, w0, w1, w2, w3);
        uint2 p0 = xb[(size_t)c0 * 32 + l];
        uint2 p1 = xb[(size_t)c1 * 32 + l];
        uint2 p2 = xb[(size_t)c2 * 32 + l];
        uint2 p3 = xb[(size_t)c3 * 32 + l];
        a0 += v0 * bflo(p0.x); a1 += v0 * bfhi(p0.x); a2 += v0 * bflo(p0.y); a3 += v0 * bfhi(p0.y);
        a0 += v1 * bflo(p1.x); a1 += v1 * bfhi(p1.x); a2 += v1 * bflo(p1.y); a3 += v1 * bfhi(p1.y);
        a0 += v2 * bflo(p2.x); a1 += v2 * bfhi(p2.x); a2 += v2 * bflo(p2.y); a3 += v2 * bfhi(p2.y);
        a0 += v3 * bflo(p3.x); a1 += v3 * bfhi(p3.x); a2 += v3 * bflo(p3.y); a3 += v3 * bfhi(p3.y);
        c0 = d0; c1 = d1; c2 = d2; c3 = d3;
        v0 = w0; v1 = w1; v2 = w2; v3 = w3;
        e = en;
    }
#undef LOADG

    // combine the two half-wave partial sums (same features, disjoint edges)
    a0 += __shfl_xor(a0, 32, 64);
    a1 += __shfl_xor(a1, 32, 64);
    a2 += __shfl_xor(a2, 32, 64);
    a3 += __shfl_xor(a3, 32, 64);

    if (h == 0) {
        uint2 o; o.x = pack2(a0, a1); o.y = pack2(a2, a3);
        nb[(size_t)n * 32 + l] = o;
    }
}

// --- K4: out = normalize([xb, nb] @ W^T + b) -------------------------------
// block = 256 = 4 waves; wave: 16 rows x 128 cols, K=256 via MFMA 16x16x32.
// A frag: lane -> row r0+(lane&15), k-chunk (lane>>4)*8 within ks*32.
// B frag: fragment-major Wf, coalesced + identical across waves.
// C/D: col = lane&15 (+16*t), row = (lane>>4)*4 + reg   [m89 layout]
__global__ __launch_bounds__(256) void gemm_norm_kernel(
        const unsigned short* __restrict__ xb, const unsigned short* __restrict__ nb,
        const bf16x8_t* __restrict__ Wf, const float* __restrict__ b,
        float* __restrict__ out, int Nn) {
    int lane = threadIdx.x & 63;
    int wave = threadIdx.x >> 6;
    int m    = lane & 15;
    int quad = lane >> 4;
    int r0   = (blockIdx.x * 4 + wave) * 16;

    int arow = r0 + m;
    if (arow >= Nn) arow = Nn - 1;       // clamp; stores guarded below
    const bf16x8_t* Ax = (const bf16x8_t*)(xb + (size_t)arow * 128);
    const bf16x8_t* An = (const bf16x8_t*)(nb + (size_t)arow * 128);

    bf16x8_t a[8];
#pragma unroll
    for (int ks = 0; ks < 4; ++ks) a[ks]     = Ax[ks * 4 + quad];
#pragma unroll
    for (int ks = 0; ks < 4; ++ks) a[4 + ks] = An[ks * 4 + quad];

    f32x4_t acc[8];
#pragma unroll
    for (int t = 0; t < 8; ++t) acc[t] = (f32x4_t){0.f, 0.f, 0.f, 0.f};

#pragma unroll
    for (int t = 0; t < 8; ++t) {
#pragma unroll
        for (int ks = 0; ks < 8; ++ks) {
            acc[t] = __builtin_amdgcn_mfma_f32_16x16x32_bf16(
                a[ks], Wf[(t * 8 + ks) * 64 + lane], acc[t], 0, 0, 0);
        }
    }

    float bc[8];
#pragma unroll
    for (int t = 0; t < 8; ++t) bc[t] = b[t * 16 + m];

    float sq[4] = {0.f, 0.f, 0.f, 0.f};
#pragma unroll
    for (int t = 0; t < 8; ++t)
#pragma unroll
        for (int r = 0; r < 4; ++r) {
            float v = acc[t][r] + bc[t];
            sq[r] += v * v;
        }
#pragma unroll
    for (int off = 1; off <= 8; off <<= 1) {
#pragma unroll
        for (int r = 0; r < 4; ++r) sq[r] += __shfl_xor(sq[r], off, 64);
    }
    float scale[4];
#pragma unroll
    for (int r = 0; r < 4; ++r) scale[r] = 1.f / fmaxf(sqrtf(sq[r]), 1e-12f);

#pragma unroll
    for (int r = 0; r < 4; ++r) {
        int row = r0 + quad * 4 + r;
        if (row < Nn) {
            float* orow = out + (size_t)row * 128;
#pragma unroll
            for (int t = 0; t < 8; ++t) {
                float v = acc[t][r] + bc[t];
                orow[t * 16 + m] = v * scale[r];
            }
        }
    }
}

extern "C" void kernel_launch(void* const* d_in, const int* in_sizes, int n_in,
                              void* d_out, int out_size, void* d_ws, size_t ws_size,
                              hipStream_t stream) {
    const float* x    = (const float*)d_in[0];
    const int*   rows = (const int*)  d_in[1];
    const int*   cols = (const int*)  d_in[2];
    const float* vals = (const float*)d_in[3];
    const float* W    = (const float*)d_in[4];
    const float* b    = (const float*)d_in[5];
    float*       out  = (float*)d_out;

    const int Nn = in_sizes[0] / 128;    // 100000
    const int Ee = in_sizes[1];          // 1600000

    char* ws = (char*)d_ws;
    int*   row_ptr = (int*)ws;
    uint4* Wf      = (uint4*)(ws + 448 * 1024);
    uint2* xb      = (uint2*)(ws + 640 * 1024);
    uint2* nb      = (uint2*)(ws + 640 * 1024 + (size_t)Nn * 256);

    rowptr_kernel<<<(Nn + 256) / 256, 256, 0, stream>>>(rows, row_ptr, Nn, Ee);
    wcast_kernel<<<16, 256, 0, stream>>>(W, Wf);
    xcast_kernel<<<(Nn * 32 + 255) / 256, 256, 0, stream>>>(x, xb, Nn * 32);
    agg_kernel<<<Nn, 64, 0, stream>>>(row_ptr, cols, vals, xb, nb);
    gemm_norm_kernel<<<(Nn + 63) / 64, 256, 0, stream>>>(
        (const unsigned short*)xb, (const unsigned short*)nb,
        (const bf16x8_t*)Wf, b, out, Nn);
}